// Round 1
// baseline (634.004 us; speedup 1.0000x reference)
//
#include <hip/hip_runtime.h>

#define NTOK 98
#define DIM 192
#define HEADS 6
#define SCALE 0.17677669529663687f

using shortx8 = __attribute__((ext_vector_type(8))) short;
using floatx4 = __attribute__((ext_vector_type(4))) float;

static __device__ __forceinline__ unsigned short f2bf(float f) {
    unsigned u = __float_as_uint(f);
    u += 0x7FFFu + ((u >> 16) & 1u);   // RNE
    return (unsigned short)(u >> 16);
}

static __device__ __forceinline__ shortx8 pack8(const float* p, float scale) {
    float4 a = *(const float4*)p;
    float4 b = *(const float4*)(p + 4);
    shortx8 t;
    t[0] = (short)f2bf(a.x * scale); t[1] = (short)f2bf(a.y * scale);
    t[2] = (short)f2bf(a.z * scale); t[3] = (short)f2bf(a.w * scale);
    t[4] = (short)f2bf(b.x * scale); t[5] = (short)f2bf(b.y * scale);
    t[6] = (short)f2bf(b.z * scale); t[7] = (short)f2bf(b.w * scale);
    return t;
}

// ---------------- prep: bias gather + weight bf16 fragment-linear layouts ----------------
// kvB[((ks*24+NT)*64+lane)*8+jj] = kv_w[(ks*32+quad*8+jj)*384 + NT*16+(lane&15)]
// pB [((ks*12+NT)*64+lane)*8+jj] = proj_w[(ks*32+quad*8+jj)*192 + NT*16+(lane&15)]
__global__ void prep_kernel(const float* __restrict__ rpb, const int* __restrict__ relidx,
                            const float* __restrict__ kvw, const float* __restrict__ pw,
                            float* __restrict__ biasF, unsigned short* __restrict__ kvB,
                            unsigned short* __restrict__ pB) {
    int e = blockIdx.x * 256 + threadIdx.x;
    if (e < HEADS * NTOK * NTOK) {
        int h = e / (NTOK * NTOK), ij = e % (NTOK * NTOK);
        biasF[e] = rpb[relidx[ij] * HEADS + h];
    }
    if (e < 73728) {
        int jj = e & 7, lane = (e >> 3) & 63, t = e >> 9;
        int NT = t % 24, ks = t / 24;
        int c = ks * 32 + (lane >> 4) * 8 + jj;
        int n = NT * 16 + (lane & 15);
        kvB[e] = f2bf(kvw[c * 384 + n]);
    }
    if (e < 36864) {
        int jj = e & 7, lane = (e >> 3) & 63, t = e >> 9;
        int NT = t % 12, ks = t / 12;
        int c = ks * 32 + (lane >> 4) * 8 + jj;
        int n = NT * 16 + (lane & 15);
        pB[e] = f2bf(pw[c * 192 + n]);
    }
}

// ---------------- fused: kv-GEMM + QK + softmax + PV (6 heads) + proj, one block/window ----
// LDS (shorts): kB [2][7][64][8] @0      (7168)   k B-frags, double-buffered by head parity
//               vB [2][2][4][64][8] @7168 (8192)  v B-frags, double-buffered
//               PA [7][4][64][8] @15360  (14336)  P A-frags (per head, reused)
//               O_lds [7][6][64][8] @0   (21504)  aliases kB/vB/PA after final barrier
__global__ __launch_bounds__(448, 4) void fused_kernel(
    const float* __restrict__ skip, const float* __restrict__ xup,
    const float* __restrict__ mask, const float* __restrict__ kv_b,
    const float* __restrict__ biasF, const unsigned short* __restrict__ kvB,
    const unsigned short* __restrict__ pB, const float* __restrict__ pb,
    float* __restrict__ out) {

    __shared__ __align__(16) unsigned short lds[29696];
    unsigned short* kB  = lds;           // [p][tj][lane][8]
    unsigned short* vB  = lds + 7168;    // [p][nt][ks][lane][8]
    unsigned short* PAb = lds + 15360;   // [mt][ks][lane][8]

    const int tid  = threadIdx.x;
    const int w    = tid >> 6;        // wave id = mtile
    const int lane = tid & 63;
    const int l15  = lane & 15;
    const int quad = lane >> 4;
    const int win  = blockIdx.x;

    // zero pad slabs: v tokens 98..127 (ks=3, both buffers/tiles); P cols 112..127
    for (int e = tid; e < 2048; e += 448) {
        int pt = e >> 9, off = e & 511;
        vB[pt * 2048 + 3 * 512 + off] = 0;
    }
    for (int e = tid; e < 7 * 256; e += 448)
        PAb[(e / 256) * 2048 + 3 * 512 + 256 + (e & 255)] = 0;

    const int mA  = w * 16 + l15;          // A-frag row (token)
    const int mAc = mA < NTOK ? mA : 97;   // clamp pad rows (finite, discarded later)

    // skip rows for this wave's mtile, all K=192 -> regs (reused by all 6 heads)
    shortx8 afr[6];
    {
        const float* sr = skip + ((size_t)win * NTOK + mAc) * DIM + quad * 8;
        #pragma unroll
        for (int ks = 0; ks < 6; ++ks) afr[ks] = pack8(sr + ks * 32, 1.0f);
    }

    const float* mw = mask + (size_t)(win & 63) * NTOK * NTOK;
    unsigned opk[12][2];   // O packed bf16: [h*2+nt][pair], pair=(r0,r1)/(r2,r3)

    #pragma unroll
    for (int h = 0; h < 6; ++h) {
        const int p = h & 1;

        // q A-frag (scaled) direct from global — issue early, hidden under kv MFMAs
        shortx8 qf = pack8(xup + ((size_t)win * NTOK + mAc) * DIM + h * 32 + quad * 8, SCALE);

        // ---- kv slice GEMM for this head: k tiles NT=2h+t, v tiles NT=12+2h+t ----
        floatx4 ak[2], av[2];
        #pragma unroll
        for (int t = 0; t < 2; ++t) {
            const int NT = 2 * h + t;
            const float cb = kv_b[NT * 16 + l15];
            floatx4 acc = {cb, cb, cb, cb};
            #pragma unroll
            for (int ks = 0; ks < 6; ++ks) {
                shortx8 bf = *(const shortx8*)(kvB + ((size_t)((ks * 24 + NT) * 64 + lane)) * 8);
                acc = __builtin_amdgcn_mfma_f32_16x16x32_bf16(afr[ks], bf, acc, 0, 0, 0);
            }
            ak[t] = acc;
        }
        #pragma unroll
        for (int t = 0; t < 2; ++t) {
            const int NT = 12 + 2 * h + t;
            const float cb = kv_b[NT * 16 + l15];
            floatx4 acc = {cb, cb, cb, cb};
            #pragma unroll
            for (int ks = 0; ks < 6; ++ks) {
                shortx8 bf = *(const shortx8*)(kvB + ((size_t)((ks * 24 + NT) * 64 + lane)) * 8);
                acc = __builtin_amdgcn_mfma_f32_16x16x32_bf16(afr[ks], bf, acc, 0, 0, 0);
            }
            av[t] = acc;
        }
        // k -> kB[p] (B-frag for QK; pad rows written too: finite row-97 copies)
        #pragma unroll
        for (int t = 0; t < 2; ++t) {
            const int dh = t * 16 + l15;
            const int base = p * 3584 + (w * 64) * 8 + (dh & 7);
            const int lphi = ((dh >> 3) & 3) << 4;
            #pragma unroll
            for (int r = 0; r < 4; ++r) {
                int mm = quad * 4 + r;
                kB[base + (mm | lphi) * 8] = f2bf(ak[t][r]);
            }
        }
        // v -> vB[p] (B-frag for PV: token on K axis)
        #pragma unroll
        for (int t = 0; t < 2; ++t) {
            #pragma unroll
            for (int r = 0; r < 4; ++r) {
                int m = w * 16 + quad * 4 + r;
                if (m < NTOK) {
                    int lp = l15 | (((m >> 3) & 3) << 4);
                    vB[p * 4096 + ((t * 4 + (m >> 5)) * 64 + lp) * 8 + (m & 7)] = f2bf(av[t][r]);
                }
            }
        }
        __syncthreads();   // S1: kB/vB[p] visible (also separates from prev head's PV)

        // ---- C-init: bias + mask (pad cols -> -1e30 so softmax -> exact 0) ----
        floatx4 S[7];
        const float* bh = biasF + h * NTOK * NTOK;
        #pragma unroll
        for (int nt = 0; nt < 7; ++nt) {
            const int j = nt * 16 + l15;
            #pragma unroll
            for (int r = 0; r < 4; ++r) {
                int i = w * 16 + quad * 4 + r;
                int ic = i < NTOK ? i : 97;
                S[nt][r] = (j < NTOK) ? (bh[ic * NTOK + j] + mw[ic * NTOK + j]) : -1e30f;
            }
        }
        // QK: S += q . k^T
        #pragma unroll
        for (int nt = 0; nt < 7; ++nt) {
            shortx8 bk = *(const shortx8*)&kB[p * 3584 + (nt * 64 + lane) * 8];
            S[nt] = __builtin_amdgcn_mfma_f32_16x16x32_bf16(qf, bk, S[nt], 0, 0, 0);
        }
        // softmax in registers; keep P unnormalized, fold 1/sum into PV epilogue
        float inv[4];
        #pragma unroll
        for (int r = 0; r < 4; ++r) {
            float mx = S[0][r];
            #pragma unroll
            for (int nt = 1; nt < 7; ++nt) mx = fmaxf(mx, S[nt][r]);
            mx = fmaxf(mx, __shfl_xor(mx, 1));
            mx = fmaxf(mx, __shfl_xor(mx, 2));
            mx = fmaxf(mx, __shfl_xor(mx, 4));
            mx = fmaxf(mx, __shfl_xor(mx, 8));
            float sm = 0.f;
            #pragma unroll
            for (int nt = 0; nt < 7; ++nt) { float ev = __expf(S[nt][r] - mx); S[nt][r] = ev; sm += ev; }
            sm += __shfl_xor(sm, 1);
            sm += __shfl_xor(sm, 2);
            sm += __shfl_xor(sm, 4);
            sm += __shfl_xor(sm, 8);
            inv[r] = 1.0f / sm;
        }
        // P -> PA (A-frag layout, unnormalized)
        #pragma unroll
        for (int nt = 0; nt < 7; ++nt) {
            const int j = nt * 16 + l15;
            const int ks = nt >> 1;
            const int lphi = ((j >> 3) & 3) << 4;
            #pragma unroll
            for (int r = 0; r < 4; ++r) {
                int mm = quad * 4 + r;
                PAb[((w * 4 + ks) * 64 + (mm | lphi)) * 8 + (j & 7)] = f2bf(S[nt][r]);
            }
        }
        __syncthreads();   // S2: PA visible

        // ---- PV: O[m][dh] = P @ v, normalize with inv, pack bf16 into regs ----
        shortx8 pa[4];
        #pragma unroll
        for (int ks = 0; ks < 4; ++ks)
            pa[ks] = *(const shortx8*)&PAb[((w * 4 + ks) * 64 + lane) * 8];
        #pragma unroll
        for (int nt = 0; nt < 2; ++nt) {
            floatx4 o = {0.f, 0.f, 0.f, 0.f};
            #pragma unroll
            for (int ks = 0; ks < 4; ++ks) {
                shortx8 vb = *(const shortx8*)&vB[p * 4096 + ((nt * 4 + ks) * 64 + lane) * 8];
                o = __builtin_amdgcn_mfma_f32_16x16x32_bf16(pa[ks], vb, o, 0, 0, 0);
            }
            opk[h * 2 + nt][0] = (unsigned)f2bf(o[0] * inv[0]) | ((unsigned)f2bf(o[1] * inv[1]) << 16);
            opk[h * 2 + nt][1] = (unsigned)f2bf(o[2] * inv[2]) | ((unsigned)f2bf(o[3] * inv[3]) << 16);
        }
        // next head's kB/vB[p^1] writes may start immediately: disjoint from
        // anything still being read in this head (PA, vB[p]); barriers S1/S2 cover the rest
    }

    __syncthreads();   // all PV LDS reads done -> repurpose lds as O_lds

    // O (regs, bf16) -> O_lds in proj A-frag layout [mt][ks=h][lane'][jj]
    #pragma unroll
    for (int h = 0; h < 6; ++h)
        #pragma unroll
        for (int nt = 0; nt < 2; ++nt)
            #pragma unroll
            for (int r = 0; r < 4; ++r) {
                int mm = quad * 4 + r;
                int dsub = nt * 16 + l15;
                unsigned v = opk[h * 2 + nt][r >> 1] >> ((r & 1) * 16);
                lds[((w * 6 + h) * 64 + (mm | (((dsub >> 3) & 3) << 4))) * 8 + (dsub & 7)] =
                    (unsigned short)v;
            }
    __syncthreads();

    // ---- proj: out = O @ proj_w + proj_b ----
    shortx8 oa[6];
    #pragma unroll
    for (int ks = 0; ks < 6; ++ks)
        oa[ks] = *(const shortx8*)&lds[((w * 6 + ks) * 64 + lane) * 8];
    float* obase = out + (size_t)win * NTOK * DIM;
    #pragma unroll
    for (int nt = 0; nt < 12; ++nt) {
        const int n = nt * 16 + l15;
        const float bb = pb[n];
        floatx4 acc = {bb, bb, bb, bb};
        #pragma unroll
        for (int ks = 0; ks < 6; ++ks) {
            shortx8 bf = *(const shortx8*)(pB + ((size_t)((ks * 12 + nt) * 64 + lane)) * 8);
            acc = __builtin_amdgcn_mfma_f32_16x16x32_bf16(oa[ks], bf, acc, 0, 0, 0);
        }
        #pragma unroll
        for (int r = 0; r < 4; ++r) {
            int m = w * 16 + quad * 4 + r;
            if (m < NTOK) obase[m * DIM + n] = acc[r];
        }
    }
}

extern "C" void kernel_launch(void* const* d_in, const int* in_sizes, int n_in,
                              void* d_out, int out_size, void* d_ws, size_t ws_size,
                              hipStream_t stream) {
    const float* skip   = (const float*)d_in[0];
    const float* x_up   = (const float*)d_in[1];
    const float* mask   = (const float*)d_in[2];
    const float* kv_w   = (const float*)d_in[3];
    const float* kv_b   = (const float*)d_in[4];
    const float* proj_w = (const float*)d_in[5];
    const float* proj_b = (const float*)d_in[6];
    const float* rpb    = (const float*)d_in[7];
    const int*   relidx = (const int*)d_in[8];
    float* out = (float*)d_out;

    float*          biasF = (float*)d_ws;                               // 230496 B
    unsigned short* kvB   = (unsigned short*)((char*)d_ws + 230496);    // 147456 B
    unsigned short* pB    = (unsigned short*)((char*)d_ws + 377952);    //  73728 B

    prep_kernel<<<288, 256, 0, stream>>>(rpb, relidx, kv_w, proj_w, biasF, kvB, pB);
    fused_kernel<<<1024, 448, 0, stream>>>(skip, x_up, mask, kv_b, biasF, kvB, pB, proj_b, out);
}

// Round 3
// 404.567 us; speedup vs baseline: 1.5671x; 1.5671x over previous
//
#include <hip/hip_runtime.h>

#define NTOK 98
#define DIM 192
#define HEADS 6
#define SCALE 0.17677669529663687f

using shortx8 = __attribute__((ext_vector_type(8))) short;
using floatx4 = __attribute__((ext_vector_type(4))) float;

static __device__ __forceinline__ unsigned short f2bf(float f) {
    unsigned u = __float_as_uint(f);
    u += 0x7FFFu + ((u >> 16) & 1u);   // RNE
    return (unsigned short)(u >> 16);
}

static __device__ __forceinline__ shortx8 pack8(const float* p, float scale) {
    float4 a = *(const float4*)p;
    float4 b = *(const float4*)(p + 4);
    shortx8 t;
    t[0] = (short)f2bf(a.x * scale); t[1] = (short)f2bf(a.y * scale);
    t[2] = (short)f2bf(a.z * scale); t[3] = (short)f2bf(a.w * scale);
    t[4] = (short)f2bf(b.x * scale); t[5] = (short)f2bf(b.y * scale);
    t[6] = (short)f2bf(b.z * scale); t[7] = (short)f2bf(b.w * scale);
    return t;
}

// ---------------- prep: bias gather + weight bf16 fragment-linear layouts ----------------
// kvB[((ks*24+NT)*64+lane)*8+jj] = kv_w[(ks*32+quad*8+jj)*384 + NT*16+(lane&15)]
// pB [((ks*12+NT)*64+lane)*8+jj] = proj_w[(ks*32+quad*8+jj)*192 + NT*16+(lane&15)]
__global__ void prep_kernel(const float* __restrict__ rpb, const int* __restrict__ relidx,
                            const float* __restrict__ kvw, const float* __restrict__ pw,
                            float* __restrict__ biasF, unsigned short* __restrict__ kvB,
                            unsigned short* __restrict__ pB) {
    int e = blockIdx.x * 256 + threadIdx.x;
    if (e < HEADS * NTOK * NTOK) {
        int h = e / (NTOK * NTOK), ij = e % (NTOK * NTOK);
        biasF[e] = rpb[relidx[ij] * HEADS + h];
    }
    if (e < 73728) {
        int jj = e & 7, lane = (e >> 3) & 63, t = e >> 9;
        int NT = t % 24, ks = t / 24;
        int c = ks * 32 + (lane >> 4) * 8 + jj;
        int n = NT * 16 + (lane & 15);
        kvB[e] = f2bf(kvw[c * 384 + n]);
    }
    if (e < 36864) {
        int jj = e & 7, lane = (e >> 3) & 63, t = e >> 9;
        int NT = t % 12, ks = t / 12;
        int c = ks * 32 + (lane >> 4) * 8 + jj;
        int n = NT * 16 + (lane & 15);
        pB[e] = f2bf(pw[c * 192 + n]);
    }
}

// ---------------- fused: per window, 2 head-groups of 3; O kept in regs; single proj ------
// lds (shorts, 74752 B total -> 2 blocks/CU):
//   kB3 @0     [3][7][64][8]      (10752)  k B-frags for current group
//   vB3 @10752 [3][2][4][64][8]   (12288)  v B-frags for current group
//   PAb @23040 [7][4][64][8]      (14336)  P A-frags (wave-private slabs)
//   O_lds @0   [7][6][64][8]      (21504)  aliases kB3+vB3 after final barrier
// __launch_bounds__(448,2): 2 blocks/CU (LDS-bound anyway) -> VGPR budget 128, not 64.
__global__ __launch_bounds__(448, 2) void fused_kernel(
    const float* __restrict__ skip, const float* __restrict__ xup,
    const float* __restrict__ mask, const float* __restrict__ kv_b,
    const float* __restrict__ biasF, const unsigned short* __restrict__ kvB,
    const unsigned short* __restrict__ pB, const float* __restrict__ pb,
    float* __restrict__ out) {

    __shared__ __align__(16) unsigned short lds[37376];
    unsigned short* kB3 = lds;
    unsigned short* vB3 = lds + 10752;
    unsigned short* PAb = lds + 23040;

    const int tid  = threadIdx.x;
    const int w    = tid >> 6;        // wave id = mtile
    const int lane = tid & 63;
    const int l15  = lane & 15;
    const int quad = lane >> 4;
    const int win  = blockIdx.x;

    // zero pad slabs once: v tokens 98..127 (ks=3 sub-slab of each (hh,ntv)); P cols 112..127
    for (int e = tid; e < 6 * 512; e += 448)
        vB3[(e >> 9) * 2048 + 3 * 512 + (e & 511)] = 0;
    for (int e = tid; e < 7 * 256; e += 448)
        PAb[(e >> 8) * 2048 + 3 * 512 + 256 + (e & 255)] = 0;
    __syncthreads();   // pad zeros visible before any staging store/read (race fix)

    const int mA  = w * 16 + l15;          // A-frag row (token)
    const int mAc = mA < NTOK ? mA : 97;   // clamp pad rows (finite, discarded later)

    const float* mw = mask + (size_t)(win & 63) * NTOK * NTOK;
    unsigned opk[12][2];   // O packed bf16: [h*2+nt][pair], pair=(r0,r1)/(r2,r3)

    #pragma unroll
    for (int g = 0; g < 2; ++g) {
        if (g) __syncthreads();   // S_pre: group-0 PV reads of kB3/vB3 done before re-stage

        // ---- stage k,v for heads 3g..3g+2 (afr live only inside this scope) ----
        {
            shortx8 afr[6];
            const float* sr = skip + ((size_t)win * NTOK + mAc) * DIM + quad * 8;
            #pragma unroll
            for (int ks = 0; ks < 6; ++ks) afr[ks] = pack8(sr + ks * 32, 1.0f);
            #pragma unroll
            for (int nt = 0; nt < 12; ++nt) {
                const int NTg = (nt < 6) ? (6 * g + nt) : (6 + 6 * g + nt);
                const float cb = kv_b[NTg * 16 + l15];
                floatx4 acc = {cb, cb, cb, cb};
                #pragma unroll
                for (int ks = 0; ks < 6; ++ks) {
                    shortx8 bf = *(const shortx8*)(kvB + ((size_t)((ks * 24 + NTg) * 64 + lane)) * 8);
                    acc = __builtin_amdgcn_mfma_f32_16x16x32_bf16(afr[ks], bf, acc, 0, 0, 0);
                }
                if (nt < 6) {  // k -> kB3 (B-frag for QK)
                    const int ch = nt * 16 + l15, hh = ch >> 5, dh = ch & 31;
                    const int base = ((hh * 7 + w) * 64) * 8 + (dh & 7);
                    const int lphi = ((dh >> 3) & 3) << 4;
                    #pragma unroll
                    for (int r = 0; r < 4; ++r) {
                        int mm = quad * 4 + r;   // pad rows written too: finite row-97 copies
                        kB3[base + (mm | lphi) * 8] = f2bf(acc[r]);
                    }
                } else {       // v -> vB3 (B-frag for PV, token on K axis)
                    const int cv = (nt - 6) * 16 + l15, hh = cv >> 5, dh = cv & 31, ntv = dh >> 4;
                    #pragma unroll
                    for (int r = 0; r < 4; ++r) {
                        int m = w * 16 + quad * 4 + r;
                        if (m < NTOK) {
                            int lp = (dh & 15) | (((m >> 3) & 3) << 4);
                            vB3[(((hh * 2 + ntv) * 4 + (m >> 5)) * 64 + lp) * 8 + (m & 7)] = f2bf(acc[r]);
                        }
                    }
                }
            }
        }
        __syncthreads();   // S_stage: kB3/vB3 visible

        // ---- 3 heads: QK + softmax + PV (PAb slabs are wave-private: no barriers) ----
        #pragma unroll
        for (int hp = 0; hp < 3; ++hp) {
            const int h = 3 * g + hp;
            shortx8 qf = pack8(xup + ((size_t)win * NTOK + mAc) * DIM + h * 32 + quad * 8, SCALE);

            floatx4 S[7];
            const float* bh = biasF + h * NTOK * NTOK;
            #pragma unroll
            for (int nt = 0; nt < 7; ++nt) {
                const int j = nt * 16 + l15;
                #pragma unroll
                for (int r = 0; r < 4; ++r) {
                    int i = w * 16 + quad * 4 + r;
                    int ic = i < NTOK ? i : 97;
                    S[nt][r] = (j < NTOK) ? (bh[ic * NTOK + j] + mw[ic * NTOK + j]) : -1e30f;
                }
            }
            #pragma unroll
            for (int nt = 0; nt < 7; ++nt) {
                shortx8 bk = *(const shortx8*)&kB3[((hp * 7 + nt) * 64 + lane) * 8];
                S[nt] = __builtin_amdgcn_mfma_f32_16x16x32_bf16(qf, bk, S[nt], 0, 0, 0);
            }
            // softmax in registers; P kept unnormalized, 1/sum folded into PV epilogue
            float inv[4];
            #pragma unroll
            for (int r = 0; r < 4; ++r) {
                float mx = S[0][r];
                #pragma unroll
                for (int nt = 1; nt < 7; ++nt) mx = fmaxf(mx, S[nt][r]);
                mx = fmaxf(mx, __shfl_xor(mx, 1));
                mx = fmaxf(mx, __shfl_xor(mx, 2));
                mx = fmaxf(mx, __shfl_xor(mx, 4));
                mx = fmaxf(mx, __shfl_xor(mx, 8));
                float sm = 0.f;
                #pragma unroll
                for (int nt = 0; nt < 7; ++nt) { float ev = __expf(S[nt][r] - mx); S[nt][r] = ev; sm += ev; }
                sm += __shfl_xor(sm, 1);
                sm += __shfl_xor(sm, 2);
                sm += __shfl_xor(sm, 4);
                sm += __shfl_xor(sm, 8);
                inv[r] = 1.0f / sm;
            }
            // P -> PAb (wave-private A-frag layout)
            #pragma unroll
            for (int nt = 0; nt < 7; ++nt) {
                const int j = nt * 16 + l15;
                const int ks = nt >> 1;
                const int lphi = ((j >> 3) & 3) << 4;
                #pragma unroll
                for (int r = 0; r < 4; ++r) {
                    int mm = quad * 4 + r;
                    PAb[((w * 4 + ks) * 64 + (mm | lphi)) * 8 + (j & 7)] = f2bf(S[nt][r]);
                }
            }
            // PV (same-wave ds_write->ds_read: compiler inserts lgkmcnt)
            shortx8 pa[4];
            #pragma unroll
            for (int ks = 0; ks < 4; ++ks)
                pa[ks] = *(const shortx8*)&PAb[((w * 4 + ks) * 64 + lane) * 8];
            #pragma unroll
            for (int nt = 0; nt < 2; ++nt) {
                floatx4 o = {0.f, 0.f, 0.f, 0.f};
                #pragma unroll
                for (int ks = 0; ks < 4; ++ks) {
                    shortx8 vb = *(const shortx8*)&vB3[(((hp * 2 + nt) * 4 + ks) * 64 + lane) * 8];
                    o = __builtin_amdgcn_mfma_f32_16x16x32_bf16(pa[ks], vb, o, 0, 0, 0);
                }
                opk[h * 2 + nt][0] = (unsigned)f2bf(o[0] * inv[0]) | ((unsigned)f2bf(o[1] * inv[1]) << 16);
                opk[h * 2 + nt][1] = (unsigned)f2bf(o[2] * inv[2]) | ((unsigned)f2bf(o[3] * inv[3]) << 16);
            }
        }
    }

    __syncthreads();   // all PV LDS reads done -> repurpose lds[0..21503] as O_lds

    // O (regs, bf16) -> O_lds in proj A-frag layout [mt][ks=h][lane'][jj] (wave-private slabs)
    #pragma unroll
    for (int h = 0; h < 6; ++h)
        #pragma unroll
        for (int nt = 0; nt < 2; ++nt)
            #pragma unroll
            for (int r = 0; r < 4; ++r) {
                int mm = quad * 4 + r;
                int dsub = nt * 16 + l15;
                unsigned v = opk[h * 2 + nt][r >> 1] >> ((r & 1) * 16);
                lds[((w * 6 + h) * 64 + (mm | (((dsub >> 3) & 3) << 4))) * 8 + (dsub & 7)] =
                    (unsigned short)v;
            }
    // same-wave write->read: no barrier needed

    // ---- proj: out = O @ proj_w + proj_b (single write of out) ----
    shortx8 oa[6];
    #pragma unroll
    for (int ks = 0; ks < 6; ++ks)
        oa[ks] = *(const shortx8*)&lds[((w * 6 + ks) * 64 + lane) * 8];
    float* obase = out + (size_t)win * NTOK * DIM;
    #pragma unroll
    for (int nt = 0; nt < 12; ++nt) {
        const int n = nt * 16 + l15;
        const float bb = pb[n];
        floatx4 acc = {bb, bb, bb, bb};
        #pragma unroll
        for (int ks = 0; ks < 6; ++ks) {
            shortx8 bf = *(const shortx8*)(pB + ((size_t)((ks * 12 + nt) * 64 + lane)) * 8);
            acc = __builtin_amdgcn_mfma_f32_16x16x32_bf16(oa[ks], bf, acc, 0, 0, 0);
        }
        #pragma unroll
        for (int r = 0; r < 4; ++r) {
            int m = w * 16 + quad * 4 + r;
            if (m < NTOK) obase[m * DIM + n] = acc[r];
        }
    }
}

extern "C" void kernel_launch(void* const* d_in, const int* in_sizes, int n_in,
                              void* d_out, int out_size, void* d_ws, size_t ws_size,
                              hipStream_t stream) {
    const float* skip   = (const float*)d_in[0];
    const float* x_up   = (const float*)d_in[1];
    const float* mask   = (const float*)d_in[2];
    const float* kv_w   = (const float*)d_in[3];
    const float* kv_b   = (const float*)d_in[4];
    const float* proj_w = (const float*)d_in[5];
    const float* proj_b = (const float*)d_in[6];
    const float* rpb    = (const float*)d_in[7];
    const int*   relidx = (const int*)d_in[8];
    float* out = (float*)d_out;

    float*          biasF = (float*)d_ws;                               // 230496 B
    unsigned short* kvB   = (unsigned short*)((char*)d_ws + 230496);    // 147456 B
    unsigned short* pB    = (unsigned short*)((char*)d_ws + 377952);    //  73728 B

    prep_kernel<<<288, 256, 0, stream>>>(rpb, relidx, kv_w, proj_w, biasF, kvB, pB);
    fused_kernel<<<1024, 448, 0, stream>>>(skip, x_up, mask, kv_b, biasF, kvB, pB, proj_b, out);
}